// Round 8
// baseline (1093.451 us; speedup 1.0000x reference)
//
#include <hip/hip_runtime.h>

#define NN 50000
#define NE 800000
#define ETILES (NE / 128)

// ================= CSR build: hist / inv / scan / scatter =================
__global__ void hist_kernel(const int* __restrict__ recv, int* __restrict__ cnt) {
    int i = blockIdx.x * 256 + threadIdx.x;
    if (i < NE) atomicAdd(&cnt[recv[i]], 1);
}

__global__ void inv_kernel(const int* __restrict__ cnt, float* __restrict__ inv) {
    int i = blockIdx.x * 256 + threadIdx.x;
    if (i < NN) inv[i] = 1.0f / (float)max(cnt[i], 1);
}

__global__ void scan1_kernel(const int* __restrict__ cnt, int* __restrict__ excl,
                             int* __restrict__ bsum) {
    const int i = blockIdx.x * 256 + threadIdx.x;
    const int lane = threadIdx.x & 63, wid = threadIdx.x >> 6;
    int orig = (i < NN) ? cnt[i] : 0;
    int x = orig;
    #pragma unroll
    for (int off = 1; off < 64; off <<= 1) {
        int y = __shfl_up(x, off, 64);
        if (lane >= off) x += y;
    }
    __shared__ int ws[4];
    if (lane == 63) ws[wid] = x;
    __syncthreads();
    int add = 0;
    for (int w = 0; w < wid; ++w) add += ws[w];
    x += add;
    if (i < NN) excl[i] = x - orig;
    if (threadIdx.x == 255) bsum[blockIdx.x] = x;
}

__global__ void scan2_kernel(int* __restrict__ bsum, int nb) {
    const int t = threadIdx.x;
    const int lane = t & 63, wid = t >> 6;
    int orig = (t < nb) ? bsum[t] : 0;
    int x = orig;
    #pragma unroll
    for (int off = 1; off < 64; off <<= 1) {
        int y = __shfl_up(x, off, 64);
        if (lane >= off) x += y;
    }
    __shared__ int ws[4];
    if (lane == 63) ws[wid] = x;
    __syncthreads();
    int add = 0;
    for (int w = 0; w < wid; ++w) add += ws[w];
    x += add;
    __syncthreads();
    if (t < nb) bsum[t] = x - orig;
}

__global__ void scan3_kernel(int* __restrict__ excl, const int* __restrict__ bsum) {
    const int i = blockIdx.x * 256 + threadIdx.x;
    if (i < NN) excl[i] += bsum[blockIdx.x];
    if (i == 0) excl[NN] = NE;
}

__global__ void scatter_kernel(const int* __restrict__ senders, const int* __restrict__ recv,
                               const int* __restrict__ row_start,
                               int* __restrict__ cursor, int* __restrict__ eidx,
                               int* __restrict__ sid, int* __restrict__ rid) {
    int i = blockIdx.x * 256 + threadIdx.x;
    if (i < NE) {
        int r = recv[i];
        int p = row_start[r] + atomicAdd(&cursor[r], 1);
        eidx[p] = i;
        sid[p] = senders[i];
        rid[p] = r;
    }
}

// ============ fused P|Q GEMM: [P|Q] = A @ [Wp|Wq], one A pass =============
// 64-row tiles, 256 thr: te=tid&15 (4 rows each), tc=tid>>4 (8 ch of 128).
__launch_bounds__(256, 3)
__global__ void gemm_pq_kernel(const float* __restrict__ A, int M,
                               const float* __restrict__ Wp_,  // [64][64]
                               const float* __restrict__ Wq_,  // [64][64]
                               float* __restrict__ Pout, float* __restrict__ Qout) {
    __shared__ float w_lds[64 * 128];   // 32 KB, [k][c'] c'<64->P else Q
    __shared__ float e_lds[64 * 68];    // 17.4 KB
    const int tid = threadIdx.x;
    for (int i = tid; i < 8192; i += 256) {
        const int k = i >> 7, c = i & 127;
        w_lds[i] = (c < 64) ? Wp_[k * 64 + c] : Wq_[k * 64 + (c - 64)];
    }
    const int te = tid & 15;
    const int tc = tid >> 4;
    const int srow = tid >> 2, shalf = tid & 3;
    const int ntiles = (M + 63) >> 6;

    for (int t = blockIdx.x; t < ntiles; t += gridDim.x) {
        const int base = t << 6;
        __syncthreads();
        {
            int g = base + srow;
            if (g > M - 1) g = M - 1;
            const float4* src = (const float4*)(A + (size_t)g * 64) + shalf * 4;
            float4* dst = (float4*)&e_lds[srow * 68 + shalf * 16];
            #pragma unroll
            for (int j = 0; j < 4; ++j) dst[j] = src[j];
        }
        __syncthreads();

        float4 acc0[4], acc1[4];
        #pragma unroll
        for (int i = 0; i < 4; ++i) {
            acc0[i] = make_float4(0.f, 0.f, 0.f, 0.f);
            acc1[i] = make_float4(0.f, 0.f, 0.f, 0.f);
        }

        #pragma unroll 2
        for (int kq = 0; kq < 16; ++kq) {
            float evs[4][4];
            #pragma unroll
            for (int i = 0; i < 4; ++i) {
                const float4 q = *(const float4*)&e_lds[(te + 16 * i) * 68 + kq * 4];
                evs[i][0] = q.x; evs[i][1] = q.y; evs[i][2] = q.z; evs[i][3] = q.w;
            }
            #pragma unroll
            for (int j = 0; j < 4; ++j) {
                const float4 w0 = *(const float4*)&w_lds[(kq * 4 + j) * 128 + tc * 8];
                const float4 w1 = *(const float4*)&w_lds[(kq * 4 + j) * 128 + tc * 8 + 4];
                #pragma unroll
                for (int i = 0; i < 4; ++i) {
                    const float ev = evs[i][j];
                    acc0[i].x = fmaf(ev, w0.x, acc0[i].x);
                    acc0[i].y = fmaf(ev, w0.y, acc0[i].y);
                    acc0[i].z = fmaf(ev, w0.z, acc0[i].z);
                    acc0[i].w = fmaf(ev, w0.w, acc0[i].w);
                    acc1[i].x = fmaf(ev, w1.x, acc1[i].x);
                    acc1[i].y = fmaf(ev, w1.y, acc1[i].y);
                    acc1[i].z = fmaf(ev, w1.z, acc1[i].z);
                    acc1[i].w = fmaf(ev, w1.w, acc1[i].w);
                }
            }
        }

        float* __restrict__ dstbuf = (tc < 8) ? Pout : Qout;
        const int cd = (tc < 8) ? tc * 8 : (tc - 8) * 8;
        #pragma unroll
        for (int i = 0; i < 4; ++i) {
            const int g = base + te + 16 * i;
            if (g < M) {
                *(float4*)(dstbuf + (size_t)g * 64 + cd) = acc0[i];
                *(float4*)(dstbuf + (size_t)g * 64 + cd + 4) = acc1[i];
            }
        }
    }
}

// ============ CSR-fused edge GEMM + ReLU + segment-sum aggregation ========
// Round-7 skeleton; load scheduling changed only:
//  - A-rows for the block's NEXT grid-stride tile prefetched into registers
//    (issued after staging barrier, consumed at next iter's ds_write).
//    In-place safe: a block reads its own future tile before writing its
//    current one; tiles are disjoint across blocks.
//  - sid + P-gathers issued BEFORE the k-loop (consumed in epilogue) so the
//    ~600-cyc L3 gather latency hides under ~2000 cyc of FMA.
//  - Q-gathers stay in epilogue: rid is CSR-sorted -> few distinct rows per
//    tile -> L1 broadcast.
__launch_bounds__(256, 3)
__global__ void edge_csr_kernel(const float* A,
                                const int* __restrict__ gidx,   // eidx (l==0) or null
                                const float* __restrict__ W,    // [64][64]
                                const float* __restrict__ bias, // [64]
                                const float* __restrict__ P,
                                const float* __restrict__ Q,
                                const int* __restrict__ sid,
                                const int* __restrict__ rid,
                                const int* __restrict__ row_start,
                                float* out,
                                float* __restrict__ agg) {
    __shared__ float w_lds[64 * 64];
    __shared__ float e_lds[128 * 68];
    const int tid = threadIdx.x;
    for (int i = tid; i < 4096; i += 256) w_lds[i] = W[i];
    const int te = tid & 15;
    const int tc = tid >> 4;
    const int c0 = tc * 4;
    const float4 bv = *(const float4*)(bias + c0);
    const int srow = tid >> 1, shalf = tid & 1;

    // prologue: first tile's A-rows into registers (grid <= ETILES)
    float4 areg[8];
    {
        const int g = (blockIdx.x << 7) + srow;
        const int src = gidx ? gidx[g] : g;
        const float4* s4 = (const float4*)(A + (size_t)src * 64) + shalf * 8;
        #pragma unroll
        for (int j = 0; j < 8; ++j) areg[j] = s4[j];
    }

    for (int t = blockIdx.x; t < ETILES; t += gridDim.x) {
        const int base = t << 7;
        __syncthreads();   // prev iter's segsum reads of e_lds complete
        {
            float4* dst = (float4*)&e_lds[srow * 68 + shalf * 32];
            #pragma unroll
            for (int j = 0; j < 8; ++j) dst[j] = areg[j];
        }
        __syncthreads();   // tile fully staged (all A reads done -> in-place safe)

        // early-issue: sender ids, then P-gathers (consumed in epilogue)
        int s_[8];
        #pragma unroll
        for (int i = 0; i < 8; ++i) s_[i] = sid[base + te + 16 * i];
        float4 pv[8];
        #pragma unroll
        for (int i = 0; i < 8; ++i) pv[i] = *(const float4*)(P + (size_t)s_[i] * 64 + c0);

        // prefetch next tile's A-rows (consumed at next iter's ds_write)
        {
            int t2 = t + gridDim.x;
            if (t2 > ETILES - 1) t2 = t;      // harmless reload on final iter
            const int g2 = (t2 << 7) + srow;
            const int src2 = gidx ? gidx[g2] : g2;
            const float4* s4 = (const float4*)(A + (size_t)src2 * 64) + shalf * 8;
            #pragma unroll
            for (int j = 0; j < 8; ++j) areg[j] = s4[j];
        }

        float4 acc[8];
        #pragma unroll
        for (int i = 0; i < 8; ++i) acc[i] = make_float4(0.f, 0.f, 0.f, 0.f);

        #pragma unroll 2
        for (int kq = 0; kq < 16; ++kq) {
            float evs[8][4];
            #pragma unroll
            for (int i = 0; i < 8; ++i) {
                const float4 q = *(const float4*)&e_lds[(te + 16 * i) * 68 + kq * 4];
                evs[i][0] = q.x; evs[i][1] = q.y; evs[i][2] = q.z; evs[i][3] = q.w;
            }
            #pragma unroll
            for (int j = 0; j < 4; ++j) {
                const float4 wv = *(const float4*)&w_lds[(kq * 4 + j) * 64 + c0];
                #pragma unroll
                for (int i = 0; i < 8; ++i) {
                    const float ev = evs[i][j];
                    acc[i].x = fmaf(ev, wv.x, acc[i].x);
                    acc[i].y = fmaf(ev, wv.y, acc[i].y);
                    acc[i].z = fmaf(ev, wv.z, acc[i].z);
                    acc[i].w = fmaf(ev, wv.w, acc[i].w);
                }
            }
        }

        __syncthreads();   // all GEMM reads of e_lds done -> reuse for outputs

        #pragma unroll
        for (int i = 0; i < 8; ++i) {
            const int e = base + te + 16 * i;
            const int r = rid[e];
            const float4 qv = *(const float4*)(Q + (size_t)r * 64 + c0);
            float4 o;
            o.x = fmaxf(acc[i].x + bv.x + pv[i].x + qv.x, 0.f);
            o.y = fmaxf(acc[i].y + bv.y + pv[i].y + qv.y, 0.f);
            o.z = fmaxf(acc[i].z + bv.z + pv[i].z + qv.z, 0.f);
            o.w = fmaxf(acc[i].w + bv.w + pv[i].w + qv.w, 0.f);
            *(float4*)(out + (size_t)e * 64 + c0) = o;
            *(float4*)&e_lds[(te + 16 * i) * 68 + c0] = o;
        }
        __syncthreads();   // output tile fully in e_lds

        const int v0 = rid[base];
        const int v1 = rid[base + 127];
        const int nv = v1 - v0 + 1;
        for (int idx = tid; idx < nv * 16; idx += 256) {
            const int v  = v0 + (idx >> 4);
            const int cg = (idx & 15) * 4;
            int lo = row_start[v], hi = row_start[v + 1];
            lo = lo > base ? lo : base;
            hi = hi < base + 128 ? hi : base + 128;
            if (lo < hi) {
                float4 sum = make_float4(0.f, 0.f, 0.f, 0.f);
                for (int j = lo - base; j < hi - base; ++j) {
                    const float4 ev = *(const float4*)&e_lds[j * 68 + cg];
                    sum.x += ev.x; sum.y += ev.y; sum.z += ev.z; sum.w += ev.w;
                }
                float* ap = agg + (size_t)v * 64 + cg;
                atomicAdd(ap + 0, sum.x);
                atomicAdd(ap + 1, sum.y);
                atomicAdd(ap + 2, sum.z);
                atomicAdd(ap + 3, sum.w);
            }
        }
    }
}

// ====== node update: relu([nodes | agg*inv] @ Wn + bn), K=128 =============
__launch_bounds__(256, 3)
__global__ void node_kernel(const float* __restrict__ nodes_in,
                            const float* __restrict__ agg,   // raw sums
                            const float* __restrict__ inv,   // 1/max(count,1)
                            const float* __restrict__ W,     // [128][64]
                            const float* __restrict__ bias,  // [64]
                            float* __restrict__ out) {
    __shared__ float w_lds[128 * 64];
    __shared__ float e_lds[128 * 33];
    const int tid = threadIdx.x;
    for (int i = tid; i < 8192; i += 256) w_lds[i] = W[i];
    const int te = tid & 15, tc = tid >> 4, c0 = tc * 4;
    const float4 bv = *(const float4*)(bias + c0);
    const int srow = tid >> 1, shalf = tid & 1;
    const int ntiles = (NN + 127) >> 7;

    for (int t = blockIdx.x; t < ntiles; t += gridDim.x) {
        const int base = t << 7;
        float4 acc[8];
        #pragma unroll
        for (int i = 0; i < 8; ++i) acc[i] = make_float4(0.f, 0.f, 0.f, 0.f);

        #pragma unroll
        for (int c = 0; c < 4; ++c) {
            const float* src0 = (c < 2) ? nodes_in : agg;
            const int coff = (c & 1) * 32;
            __syncthreads();
            {
                int g = base + srow;
                if (g > NN - 1) g = NN - 1;
                const float4* src = (const float4*)(src0 + (size_t)g * 64 + coff) + shalf * 4;
                const float scale = (c >= 2) ? inv[g] : 1.0f;
                float* dst = &e_lds[srow * 33 + shalf * 16];
                #pragma unroll
                for (int j = 0; j < 4; ++j) {
                    float4 v = src[j];
                    dst[j * 4 + 0] = v.x * scale; dst[j * 4 + 1] = v.y * scale;
                    dst[j * 4 + 2] = v.z * scale; dst[j * 4 + 3] = v.w * scale;
                }
            }
            __syncthreads();
            #pragma unroll 4
            for (int k = 0; k < 32; ++k) {
                const float4 wv = *(const float4*)&w_lds[(c * 32 + k) * 64 + c0];
                #pragma unroll
                for (int i = 0; i < 8; ++i) {
                    const float ev = e_lds[(te + 16 * i) * 33 + k];
                    acc[i].x = fmaf(ev, wv.x, acc[i].x);
                    acc[i].y = fmaf(ev, wv.y, acc[i].y);
                    acc[i].z = fmaf(ev, wv.z, acc[i].z);
                    acc[i].w = fmaf(ev, wv.w, acc[i].w);
                }
            }
        }

        #pragma unroll
        for (int i = 0; i < 8; ++i) {
            const int v = base + te + 16 * i;
            if (v < NN) {
                float4 o = acc[i];
                o.x = fmaxf(o.x + bv.x, 0.f); o.y = fmaxf(o.y + bv.y, 0.f);
                o.z = fmaxf(o.z + bv.z, 0.f); o.w = fmaxf(o.w + bv.w, 0.f);
                *(float4*)(out + (size_t)v * 64 + c0) = o;
            }
        }
    }
}

// ================= final: LN + MLP + projection (LDS-broadcast GEMMs) =====
__launch_bounds__(256, 2)
__global__ void final_kernel(const float* __restrict__ nodes,
                             const float* __restrict__ gamma,
                             const float* __restrict__ beta,
                             const float* __restrict__ W1, const float* __restrict__ b1,
                             const float* __restrict__ W2, const float* __restrict__ b2,
                             const float* __restrict__ Wp, const float* __restrict__ bp,
                             float* __restrict__ out) {
    __shared__ float w1_lds[64 * 128];
    __shared__ float w2_lds[128 * 64];
    __shared__ float x_lds[16 * 66];
    __shared__ float h_lds[16 * 130];
    const int tid = threadIdx.x;
    for (int i = tid; i < 8192; i += 256) w1_lds[i] = W1[i];
    for (int i = tid; i < 8192; i += 256) w2_lds[i] = W2[i];
    const int r  = tid >> 4;
    const int li = tid & 15;
    const float4 gm4 = *(const float4*)(gamma + li * 4);
    const float4 bt4 = *(const float4*)(beta + li * 4);
    const float4 b1v0 = *(const float4*)(b1 + li * 8);
    const float4 b1v1 = *(const float4*)(b1 + li * 8 + 4);
    const float4 b2v = *(const float4*)(b2 + li * 4);
    const float4 wpv = *(const float4*)(Wp + li * 4);
    const float bp0 = bp[0];

    for (int tile = blockIdx.x; tile < NN / 16; tile += gridDim.x) {
        const int vbase = tile * 16;
        const float4 xv = *(const float4*)(nodes + (size_t)(vbase + r) * 64 + li * 4);
        float s = xv.x + xv.y + xv.z + xv.w;
        #pragma unroll
        for (int off = 1; off < 16; off <<= 1) s += __shfl_xor(s, off, 16);
        const float mu = s * (1.0f / 64.0f);
        const float dx = xv.x - mu, dy = xv.y - mu, dz = xv.z - mu, dw = xv.w - mu;
        float q = dx * dx + dy * dy + dz * dz + dw * dw;
        #pragma unroll
        for (int off = 1; off < 16; off <<= 1) q += __shfl_xor(q, off, 16);
        const float rs = rsqrtf(q * (1.0f / 64.0f) + 1e-5f);
        float* xp = &x_lds[r * 66 + li * 4];
        xp[0] = dx * rs * gm4.x + bt4.x;
        xp[1] = dy * rs * gm4.y + bt4.y;
        xp[2] = dz * rs * gm4.z + bt4.z;
        xp[3] = dw * rs * gm4.w + bt4.w;
        __syncthreads();

        float4 h0 = make_float4(0.f, 0.f, 0.f, 0.f);
        float4 h1 = make_float4(0.f, 0.f, 0.f, 0.f);
        #pragma unroll 8
        for (int k = 0; k < 64; ++k) {
            const float xk = x_lds[r * 66 + k];
            const float4 w0 = *(const float4*)&w1_lds[k * 128 + li * 8];
            const float4 w1v = *(const float4*)&w1_lds[k * 128 + li * 8 + 4];
            h0.x = fmaf(xk, w0.x, h0.x); h0.y = fmaf(xk, w0.y, h0.y);
            h0.z = fmaf(xk, w0.z, h0.z); h0.w = fmaf(xk, w0.w, h0.w);
            h1.x = fmaf(xk, w1v.x, h1.x); h1.y = fmaf(xk, w1v.y, h1.y);
            h1.z = fmaf(xk, w1v.z, h1.z); h1.w = fmaf(xk, w1v.w, h1.w);
        }
        float* hp = &h_lds[r * 130 + li * 8];
        hp[0] = fmaxf(h0.x + b1v0.x, 0.f);
        hp[1] = fmaxf(h0.y + b1v0.y, 0.f);
        hp[2] = fmaxf(h0.z + b1v0.z, 0.f);
        hp[3] = fmaxf(h0.w + b1v0.w, 0.f);
        hp[4] = fmaxf(h1.x + b1v1.x, 0.f);
        hp[5] = fmaxf(h1.y + b1v1.y, 0.f);
        hp[6] = fmaxf(h1.z + b1v1.z, 0.f);
        hp[7] = fmaxf(h1.w + b1v1.w, 0.f);
        __syncthreads();

        float4 o = make_float4(0.f, 0.f, 0.f, 0.f);
        #pragma unroll 8
        for (int k = 0; k < 128; ++k) {
            const float hk = h_lds[r * 130 + k];
            const float4 w = *(const float4*)&w2_lds[k * 64 + li * 4];
            o.x = fmaf(hk, w.x, o.x); o.y = fmaf(hk, w.y, o.y);
            o.z = fmaf(hk, w.z, o.z); o.w = fmaf(hk, w.w, o.w);
        }
        float p = (o.x + b2v.x) * wpv.x + (o.y + b2v.y) * wpv.y +
                  (o.z + b2v.z) * wpv.z + (o.w + b2v.w) * wpv.w;
        #pragma unroll
        for (int off = 1; off < 16; off <<= 1) p += __shfl_xor(p, off, 16);
        if (li == 0) out[vbase + r] = p + bp0;
    }
}

extern "C" void kernel_launch(void* const* d_in, const int* in_sizes, int n_in,
                              void* d_out, int out_size, void* d_ws, size_t ws_size,
                              hipStream_t stream) {
    const float* nodes     = (const float*)d_in[0];
    const float* edges     = (const float*)d_in[1];
    const int*   senders   = (const int*)d_in[2];
    const int*   receivers = (const int*)d_in[3];
    const float* We        = (const float*)d_in[4];
    const float* be        = (const float*)d_in[5];
    const float* Wn        = (const float*)d_in[6];
    const float* bn        = (const float*)d_in[7];
    const float* gamma     = (const float*)d_in[8];
    const float* beta      = (const float*)d_in[9];
    const float* W1        = (const float*)d_in[10];
    const float* b1        = (const float*)d_in[11];
    const float* W2        = (const float*)d_in[12];
    const float* b2        = (const float*)d_in[13];
    const float* Wp        = (const float*)d_in[14];
    const float* bp        = (const float*)d_in[15];
    float* out = (float*)d_out;

    float* ws        = (float*)d_ws;
    float* edges_buf = ws;                                   // [NE][64]  204.8 MB (CSR order)
    float* Pbuf      = edges_buf + (size_t)NE * 64;          // [NN][64]
    float* Qbuf      = Pbuf + (size_t)NN * 64;               // [NN][64]
    float* nodes_buf = Qbuf + (size_t)NN * 64;               // [NN][64]
    float* aggbuf    = nodes_buf + (size_t)NN * 64;          // [NN][64] raw sums
    int*   cnt_i     = (int*)(aggbuf + (size_t)NN * 64);     // [NN]
    int*   row_start = cnt_i + NN;                           // [NN+1]
    int*   cursor    = row_start + NN + 1;                   // [NN]
    int*   eidx      = cursor + NN;                          // [NE]
    int*   sid       = eidx + NE;                            // [NE]
    int*   rid       = sid + NE;                             // [NE]
    int*   bsum      = rid + NE;                             // [256]
    float* inv       = (float*)(bsum + 256);                 // [NN]

    hipMemsetAsync(cnt_i, 0, NN * sizeof(int), stream);
    hipMemsetAsync(cursor, 0, NN * sizeof(int), stream);
    hist_kernel<<<(NE + 255) / 256, 256, 0, stream>>>(receivers, cnt_i);
    inv_kernel<<<(NN + 255) / 256, 256, 0, stream>>>(cnt_i, inv);
    scan1_kernel<<<196, 256, 0, stream>>>(cnt_i, row_start, bsum);
    scan2_kernel<<<1, 256, 0, stream>>>(bsum, 196);
    scan3_kernel<<<196, 256, 0, stream>>>(row_start, bsum);
    scatter_kernel<<<(NE + 255) / 256, 256, 0, stream>>>(senders, receivers, row_start,
                                                         cursor, eidx, sid, rid);

    for (int l = 0; l < 3; ++l) {
        const float* ncur = (l == 0) ? nodes : nodes_buf;
        const float* We_l = We + (size_t)l * 192 * 64;
        // [P|Q] = nodes @ [We[64:128] | We[128:192]]  (one A pass)
        gemm_pq_kernel<<<782, 256, 0, stream>>>(ncur, NN, We_l + 64 * 64, We_l + 128 * 64,
                                                Pbuf, Qbuf);
        // zero agg sums, then fused edge GEMM + aggregation (CSR order)
        hipMemsetAsync(aggbuf, 0, (size_t)NN * 64 * sizeof(float), stream);
        edge_csr_kernel<<<1563, 256, 0, stream>>>(
            (l == 0) ? edges : edges_buf,
            (l == 0) ? eidx : (const int*)nullptr,
            We_l, be + (size_t)l * 64, Pbuf, Qbuf,
            sid, rid, row_start, edges_buf, aggbuf);
        // nodes = relu([nodes | agg*inv] @ Wn + bn)
        node_kernel<<<391, 256, 0, stream>>>(ncur, aggbuf, inv,
                                             Wn + (size_t)l * 128 * 64, bn + (size_t)l * 64,
                                             nodes_buf);
    }
    final_kernel<<<625, 256, 0, stream>>>(nodes_buf, gamma, beta,
                                          W1, b1, W2, b2, Wp, bp, out);
}

// Round 9
// 795.687 us; speedup vs baseline: 1.3742x; 1.3742x over previous
//
#include <hip/hip_runtime.h>

#define NN 50000
#define NE 800000

// ================= CSR build: hist / inv / scan / scatter =================
__global__ void hist_kernel(const int* __restrict__ recv, int* __restrict__ cnt) {
    int i = blockIdx.x * 256 + threadIdx.x;
    if (i < NE) atomicAdd(&cnt[recv[i]], 1);
}

__global__ void inv_kernel(const int* __restrict__ cnt, float* __restrict__ inv) {
    int i = blockIdx.x * 256 + threadIdx.x;
    if (i < NN) inv[i] = 1.0f / (float)max(cnt[i], 1);
}

__global__ void scan1_kernel(const int* __restrict__ cnt, int* __restrict__ excl,
                             int* __restrict__ bsum) {
    const int i = blockIdx.x * 256 + threadIdx.x;
    const int lane = threadIdx.x & 63, wid = threadIdx.x >> 6;
    int orig = (i < NN) ? cnt[i] : 0;
    int x = orig;
    #pragma unroll
    for (int off = 1; off < 64; off <<= 1) {
        int y = __shfl_up(x, off, 64);
        if (lane >= off) x += y;
    }
    __shared__ int ws[4];
    if (lane == 63) ws[wid] = x;
    __syncthreads();
    int add = 0;
    for (int w = 0; w < wid; ++w) add += ws[w];
    x += add;
    if (i < NN) excl[i] = x - orig;
    if (threadIdx.x == 255) bsum[blockIdx.x] = x;
}

__global__ void scan2_kernel(int* __restrict__ bsum, int nb) {
    const int t = threadIdx.x;
    const int lane = t & 63, wid = t >> 6;
    int orig = (t < nb) ? bsum[t] : 0;
    int x = orig;
    #pragma unroll
    for (int off = 1; off < 64; off <<= 1) {
        int y = __shfl_up(x, off, 64);
        if (lane >= off) x += y;
    }
    __shared__ int ws[4];
    if (lane == 63) ws[wid] = x;
    __syncthreads();
    int add = 0;
    for (int w = 0; w < wid; ++w) add += ws[w];
    x += add;
    __syncthreads();
    if (t < nb) bsum[t] = x - orig;
}

__global__ void scan3_kernel(int* __restrict__ excl, const int* __restrict__ bsum) {
    const int i = blockIdx.x * 256 + threadIdx.x;
    if (i < NN) excl[i] += bsum[blockIdx.x];
    if (i == 0) excl[NN] = NE;
}

__global__ void scatter_kernel(const int* __restrict__ senders, const int* __restrict__ recv,
                               const int* __restrict__ row_start,
                               int* __restrict__ cursor, int* __restrict__ eidx,
                               int* __restrict__ sid, int* __restrict__ rid) {
    int i = blockIdx.x * 256 + threadIdx.x;
    if (i < NE) {
        int r = recv[i];
        int p = row_start[r] + atomicAdd(&cursor[r], 1);
        eidx[p] = i;
        sid[p] = senders[i];
        rid[p] = r;
    }
}

// ============ fused P|Q GEMM: [P|Q] = A @ [Wp|Wq], one A pass =============
__launch_bounds__(256, 3)
__global__ void gemm_pq_kernel(const float* __restrict__ A, int M,
                               const float* __restrict__ Wp_,  // [64][64]
                               const float* __restrict__ Wq_,  // [64][64]
                               float* __restrict__ Pout, float* __restrict__ Qout) {
    __shared__ float w_lds[64 * 128];   // 32 KB, [k][c'] c'<64->P else Q
    __shared__ float e_lds[64 * 68];    // 17.4 KB
    const int tid = threadIdx.x;
    for (int i = tid; i < 8192; i += 256) {
        const int k = i >> 7, c = i & 127;
        w_lds[i] = (c < 64) ? Wp_[k * 64 + c] : Wq_[k * 64 + (c - 64)];
    }
    const int te = tid & 15;
    const int tc = tid >> 4;
    const int srow = tid >> 2, shalf = tid & 3;
    const int ntiles = (M + 63) >> 6;

    for (int t = blockIdx.x; t < ntiles; t += gridDim.x) {
        const int base = t << 6;
        __syncthreads();
        {
            int g = base + srow;
            if (g > M - 1) g = M - 1;
            const float4* src = (const float4*)(A + (size_t)g * 64) + shalf * 4;
            float4* dst = (float4*)&e_lds[srow * 68 + shalf * 16];
            #pragma unroll
            for (int j = 0; j < 4; ++j) dst[j] = src[j];
        }
        __syncthreads();

        float4 acc0[4], acc1[4];
        #pragma unroll
        for (int i = 0; i < 4; ++i) {
            acc0[i] = make_float4(0.f, 0.f, 0.f, 0.f);
            acc1[i] = make_float4(0.f, 0.f, 0.f, 0.f);
        }

        #pragma unroll 2
        for (int kq = 0; kq < 16; ++kq) {
            float evs[4][4];
            #pragma unroll
            for (int i = 0; i < 4; ++i) {
                const float4 q = *(const float4*)&e_lds[(te + 16 * i) * 68 + kq * 4];
                evs[i][0] = q.x; evs[i][1] = q.y; evs[i][2] = q.z; evs[i][3] = q.w;
            }
            #pragma unroll
            for (int j = 0; j < 4; ++j) {
                const float4 w0 = *(const float4*)&w_lds[(kq * 4 + j) * 128 + tc * 8];
                const float4 w1 = *(const float4*)&w_lds[(kq * 4 + j) * 128 + tc * 8 + 4];
                #pragma unroll
                for (int i = 0; i < 4; ++i) {
                    const float ev = evs[i][j];
                    acc0[i].x = fmaf(ev, w0.x, acc0[i].x);
                    acc0[i].y = fmaf(ev, w0.y, acc0[i].y);
                    acc0[i].z = fmaf(ev, w0.z, acc0[i].z);
                    acc0[i].w = fmaf(ev, w0.w, acc0[i].w);
                    acc1[i].x = fmaf(ev, w1.x, acc1[i].x);
                    acc1[i].y = fmaf(ev, w1.y, acc1[i].y);
                    acc1[i].z = fmaf(ev, w1.z, acc1[i].z);
                    acc1[i].w = fmaf(ev, w1.w, acc1[i].w);
                }
            }
        }

        float* __restrict__ dstbuf = (tc < 8) ? Pout : Qout;
        const int cd = (tc < 8) ? tc * 8 : (tc - 8) * 8;
        #pragma unroll
        for (int i = 0; i < 4; ++i) {
            const int g = base + te + 16 * i;
            if (g < M) {
                *(float4*)(dstbuf + (size_t)g * 64 + cd) = acc0[i];
                *(float4*)(dstbuf + (size_t)g * 64 + cd + 4) = acc1[i];
            }
        }
    }
}

// ============ CSR-fused edge GEMM + ReLU + segment-sum aggregation ========
// Round-7 algorithm exactly (no reg prefetch / no early gathers — those
// spilled in round 8). Change: 512-thread blocks, thread tile 4 rows x 4 ch.
// Same 51.2 KB LDS -> 3 blocks/CU, but 24 waves/CU instead of 12 (latency
// hiding via TLP, not per-thread ILP; VGPR demand DROPS).
// In-place safe (A==out for l>=1): staging barrier orders all tile reads
// before any tile write; blocks touch disjoint tiles.
__launch_bounds__(512, 6)
__global__ void edge_csr_kernel(const float* A,
                                const int* __restrict__ gidx,   // eidx (l==0) or null
                                const float* __restrict__ W,    // [64][64]
                                const float* __restrict__ bias, // [64]
                                const float* __restrict__ P,
                                const float* __restrict__ Q,
                                const int* __restrict__ sid,
                                const int* __restrict__ rid,
                                const int* __restrict__ row_start,
                                float* out,
                                float* __restrict__ agg) {
    __shared__ float w_lds[64 * 64];      // 16 KB
    __shared__ float e_lds[128 * 68];     // 34.8 KB
    const int tid = threadIdx.x;
    for (int i = tid; i < 4096; i += 512) w_lds[i] = W[i];
    const int te = tid & 31;              // row group: rows te, te+32, te+64, te+96
    const int tc = tid >> 5;              // 0..15 channel group
    const int c0 = tc * 4;
    const float4 bv = *(const float4*)(bias + c0);
    const int srow = tid >> 2, sq = tid & 3;

    for (int t = blockIdx.x; t < NE / 128; t += gridDim.x) {
        const int base = t << 7;
        __syncthreads();   // prev iter's segsum reads of e_lds complete
        {
            const int g = base + srow;
            const int src = gidx ? gidx[g] : g;
            const float4* s4 = (const float4*)(A + (size_t)src * 64) + sq * 4;
            float4* dst = (float4*)&e_lds[srow * 68 + sq * 16];
            #pragma unroll
            for (int j = 0; j < 4; ++j) dst[j] = s4[j];
        }
        __syncthreads();   // tile fully staged; all A reads done -> in-place safe

        float4 acc[4];
        #pragma unroll
        for (int i = 0; i < 4; ++i) acc[i] = make_float4(0.f, 0.f, 0.f, 0.f);

        #pragma unroll 2
        for (int kq = 0; kq < 16; ++kq) {
            float evs[4][4];
            #pragma unroll
            for (int i = 0; i < 4; ++i) {
                const float4 q = *(const float4*)&e_lds[(te + 32 * i) * 68 + kq * 4];
                evs[i][0] = q.x; evs[i][1] = q.y; evs[i][2] = q.z; evs[i][3] = q.w;
            }
            #pragma unroll
            for (int j = 0; j < 4; ++j) {
                const float4 wv = *(const float4*)&w_lds[(kq * 4 + j) * 64 + c0];
                #pragma unroll
                for (int i = 0; i < 4; ++i) {
                    const float ev = evs[i][j];
                    acc[i].x = fmaf(ev, wv.x, acc[i].x);
                    acc[i].y = fmaf(ev, wv.y, acc[i].y);
                    acc[i].z = fmaf(ev, wv.z, acc[i].z);
                    acc[i].w = fmaf(ev, wv.w, acc[i].w);
                }
            }
        }

        __syncthreads();   // all GEMM reads of e_lds done -> reuse for outputs

        #pragma unroll
        for (int i = 0; i < 4; ++i) {
            const int e = base + te + 32 * i;
            const int s = sid[e];
            const int r = rid[e];
            const float4 pv = *(const float4*)(P + (size_t)s * 64 + c0);
            const float4 qv = *(const float4*)(Q + (size_t)r * 64 + c0);
            float4 o;
            o.x = fmaxf(acc[i].x + bv.x + pv.x + qv.x, 0.f);
            o.y = fmaxf(acc[i].y + bv.y + pv.y + qv.y, 0.f);
            o.z = fmaxf(acc[i].z + bv.z + pv.z + qv.z, 0.f);
            o.w = fmaxf(acc[i].w + bv.w + pv.w + qv.w, 0.f);
            *(float4*)(out + (size_t)e * 64 + c0) = o;
            *(float4*)&e_lds[(te + 32 * i) * 68 + c0] = o;
        }
        __syncthreads();   // output tile fully in e_lds

        // segment-sum over this tile's receiver range (rid sorted ascending)
        const int v0 = rid[base];
        const int v1 = rid[base + 127];
        const int nv = v1 - v0 + 1;
        for (int idx = tid; idx < nv * 16; idx += 512) {
            const int v  = v0 + (idx >> 4);
            const int cg = (idx & 15) * 4;
            int lo = row_start[v], hi = row_start[v + 1];
            lo = lo > base ? lo : base;
            hi = hi < base + 128 ? hi : base + 128;
            if (lo < hi) {
                float4 sum = make_float4(0.f, 0.f, 0.f, 0.f);
                for (int j = lo - base; j < hi - base; ++j) {
                    const float4 ev = *(const float4*)&e_lds[j * 68 + cg];
                    sum.x += ev.x; sum.y += ev.y; sum.z += ev.z; sum.w += ev.w;
                }
                float* ap = agg + (size_t)v * 64 + cg;
                atomicAdd(ap + 0, sum.x);
                atomicAdd(ap + 1, sum.y);
                atomicAdd(ap + 2, sum.z);
                atomicAdd(ap + 3, sum.w);
            }
        }
    }
}

// ====== node update: relu([nodes | agg*inv] @ Wn + bn), K=128 =============
__launch_bounds__(256, 3)
__global__ void node_kernel(const float* __restrict__ nodes_in,
                            const float* __restrict__ agg,   // raw sums
                            const float* __restrict__ inv,   // 1/max(count,1)
                            const float* __restrict__ W,     // [128][64]
                            const float* __restrict__ bias,  // [64]
                            float* __restrict__ out) {
    __shared__ float w_lds[128 * 64];
    __shared__ float e_lds[128 * 33];
    const int tid = threadIdx.x;
    for (int i = tid; i < 8192; i += 256) w_lds[i] = W[i];
    const int te = tid & 15, tc = tid >> 4, c0 = tc * 4;
    const float4 bv = *(const float4*)(bias + c0);
    const int srow = tid >> 1, shalf = tid & 1;
    const int ntiles = (NN + 127) >> 7;

    for (int t = blockIdx.x; t < ntiles; t += gridDim.x) {
        const int base = t << 7;
        float4 acc[8];
        #pragma unroll
        for (int i = 0; i < 8; ++i) acc[i] = make_float4(0.f, 0.f, 0.f, 0.f);

        #pragma unroll
        for (int c = 0; c < 4; ++c) {
            const float* src0 = (c < 2) ? nodes_in : agg;
            const int coff = (c & 1) * 32;
            __syncthreads();
            {
                int g = base + srow;
                if (g > NN - 1) g = NN - 1;
                const float4* src = (const float4*)(src0 + (size_t)g * 64 + coff) + shalf * 4;
                const float scale = (c >= 2) ? inv[g] : 1.0f;
                float* dst = &e_lds[srow * 33 + shalf * 16];
                #pragma unroll
                for (int j = 0; j < 4; ++j) {
                    float4 v = src[j];
                    dst[j * 4 + 0] = v.x * scale; dst[j * 4 + 1] = v.y * scale;
                    dst[j * 4 + 2] = v.z * scale; dst[j * 4 + 3] = v.w * scale;
                }
            }
            __syncthreads();
            #pragma unroll 4
            for (int k = 0; k < 32; ++k) {
                const float4 wv = *(const float4*)&w_lds[(c * 32 + k) * 64 + c0];
                #pragma unroll
                for (int i = 0; i < 8; ++i) {
                    const float ev = e_lds[(te + 16 * i) * 33 + k];
                    acc[i].x = fmaf(ev, wv.x, acc[i].x);
                    acc[i].y = fmaf(ev, wv.y, acc[i].y);
                    acc[i].z = fmaf(ev, wv.z, acc[i].z);
                    acc[i].w = fmaf(ev, wv.w, acc[i].w);
                }
            }
        }

        #pragma unroll
        for (int i = 0; i < 8; ++i) {
            const int v = base + te + 16 * i;
            if (v < NN) {
                float4 o = acc[i];
                o.x = fmaxf(o.x + bv.x, 0.f); o.y = fmaxf(o.y + bv.y, 0.f);
                o.z = fmaxf(o.z + bv.z, 0.f); o.w = fmaxf(o.w + bv.w, 0.f);
                *(float4*)(out + (size_t)v * 64 + c0) = o;
            }
        }
    }
}

// ================= final: LN + MLP + projection (LDS-broadcast GEMMs) =====
__launch_bounds__(256, 2)
__global__ void final_kernel(const float* __restrict__ nodes,
                             const float* __restrict__ gamma,
                             const float* __restrict__ beta,
                             const float* __restrict__ W1, const float* __restrict__ b1,
                             const float* __restrict__ W2, const float* __restrict__ b2,
                             const float* __restrict__ Wp, const float* __restrict__ bp,
                             float* __restrict__ out) {
    __shared__ float w1_lds[64 * 128];
    __shared__ float w2_lds[128 * 64];
    __shared__ float x_lds[16 * 66];
    __shared__ float h_lds[16 * 130];
    const int tid = threadIdx.x;
    for (int i = tid; i < 8192; i += 256) w1_lds[i] = W1[i];
    for (int i = tid; i < 8192; i += 256) w2_lds[i] = W2[i];
    const int r  = tid >> 4;
    const int li = tid & 15;
    const float4 gm4 = *(const float4*)(gamma + li * 4);
    const float4 bt4 = *(const float4*)(beta + li * 4);
    const float4 b1v0 = *(const float4*)(b1 + li * 8);
    const float4 b1v1 = *(const float4*)(b1 + li * 8 + 4);
    const float4 b2v = *(const float4*)(b2 + li * 4);
    const float4 wpv = *(const float4*)(Wp + li * 4);
    const float bp0 = bp[0];

    for (int tile = blockIdx.x; tile < NN / 16; tile += gridDim.x) {
        const int vbase = tile * 16;
        const float4 xv = *(const float4*)(nodes + (size_t)(vbase + r) * 64 + li * 4);
        float s = xv.x + xv.y + xv.z + xv.w;
        #pragma unroll
        for (int off = 1; off < 16; off <<= 1) s += __shfl_xor(s, off, 16);
        const float mu = s * (1.0f / 64.0f);
        const float dx = xv.x - mu, dy = xv.y - mu, dz = xv.z - mu, dw = xv.w - mu;
        float q = dx * dx + dy * dy + dz * dz + dw * dw;
        #pragma unroll
        for (int off = 1; off < 16; off <<= 1) q += __shfl_xor(q, off, 16);
        const float rs = rsqrtf(q * (1.0f / 64.0f) + 1e-5f);
        float* xp = &x_lds[r * 66 + li * 4];
        xp[0] = dx * rs * gm4.x + bt4.x;
        xp[1] = dy * rs * gm4.y + bt4.y;
        xp[2] = dz * rs * gm4.z + bt4.z;
        xp[3] = dw * rs * gm4.w + bt4.w;
        __syncthreads();

        float4 h0 = make_float4(0.f, 0.f, 0.f, 0.f);
        float4 h1 = make_float4(0.f, 0.f, 0.f, 0.f);
        #pragma unroll 8
        for (int k = 0; k < 64; ++k) {
            const float xk = x_lds[r * 66 + k];
            const float4 w0 = *(const float4*)&w1_lds[k * 128 + li * 8];
            const float4 w1v = *(const float4*)&w1_lds[k * 128 + li * 8 + 4];
            h0.x = fmaf(xk, w0.x, h0.x); h0.y = fmaf(xk, w0.y, h0.y);
            h0.z = fmaf(xk, w0.z, h0.z); h0.w = fmaf(xk, w0.w, h0.w);
            h1.x = fmaf(xk, w1v.x, h1.x); h1.y = fmaf(xk, w1v.y, h1.y);
            h1.z = fmaf(xk, w1v.z, h1.z); h1.w = fmaf(xk, w1v.w, h1.w);
        }
        float* hp = &h_lds[r * 130 + li * 8];
        hp[0] = fmaxf(h0.x + b1v0.x, 0.f);
        hp[1] = fmaxf(h0.y + b1v0.y, 0.f);
        hp[2] = fmaxf(h0.z + b1v0.z, 0.f);
        hp[3] = fmaxf(h0.w + b1v0.w, 0.f);
        hp[4] = fmaxf(h1.x + b1v1.x, 0.f);
        hp[5] = fmaxf(h1.y + b1v1.y, 0.f);
        hp[6] = fmaxf(h1.z + b1v1.z, 0.f);
        hp[7] = fmaxf(h1.w + b1v1.w, 0.f);
        __syncthreads();

        float4 o = make_float4(0.f, 0.f, 0.f, 0.f);
        #pragma unroll 8
        for (int k = 0; k < 128; ++k) {
            const float hk = h_lds[r * 130 + k];
            const float4 w = *(const float4*)&w2_lds[k * 64 + li * 4];
            o.x = fmaf(hk, w.x, o.x); o.y = fmaf(hk, w.y, o.y);
            o.z = fmaf(hk, w.z, o.z); o.w = fmaf(hk, w.w, o.w);
        }
        float p = (o.x + b2v.x) * wpv.x + (o.y + b2v.y) * wpv.y +
                  (o.z + b2v.z) * wpv.z + (o.w + b2v.w) * wpv.w;
        #pragma unroll
        for (int off = 1; off < 16; off <<= 1) p += __shfl_xor(p, off, 16);
        if (li == 0) out[vbase + r] = p + bp0;
    }
}

extern "C" void kernel_launch(void* const* d_in, const int* in_sizes, int n_in,
                              void* d_out, int out_size, void* d_ws, size_t ws_size,
                              hipStream_t stream) {
    const float* nodes     = (const float*)d_in[0];
    const float* edges     = (const float*)d_in[1];
    const int*   senders   = (const int*)d_in[2];
    const int*   receivers = (const int*)d_in[3];
    const float* We        = (const float*)d_in[4];
    const float* be        = (const float*)d_in[5];
    const float* Wn        = (const float*)d_in[6];
    const float* bn        = (const float*)d_in[7];
    const float* gamma     = (const float*)d_in[8];
    const float* beta      = (const float*)d_in[9];
    const float* W1        = (const float*)d_in[10];
    const float* b1        = (const float*)d_in[11];
    const float* W2        = (const float*)d_in[12];
    const float* b2        = (const float*)d_in[13];
    const float* Wp        = (const float*)d_in[14];
    const float* bp        = (const float*)d_in[15];
    float* out = (float*)d_out;

    float* ws        = (float*)d_ws;
    float* edges_buf = ws;                                   // [NE][64]  204.8 MB (CSR order)
    float* Pbuf      = edges_buf + (size_t)NE * 64;          // [NN][64]
    float* Qbuf      = Pbuf + (size_t)NN * 64;               // [NN][64]
    float* nodes_buf = Qbuf + (size_t)NN * 64;               // [NN][64]
    float* aggbuf    = nodes_buf + (size_t)NN * 64;          // [NN][64] raw sums
    int*   cnt_i     = (int*)(aggbuf + (size_t)NN * 64);     // [NN]
    int*   row_start = cnt_i + NN;                           // [NN+1]
    int*   cursor    = row_start + NN + 1;                   // [NN]
    int*   eidx      = cursor + NN;                          // [NE]
    int*   sid       = eidx + NE;                            // [NE]
    int*   rid       = sid + NE;                             // [NE]
    int*   bsum      = rid + NE;                             // [256]
    float* inv       = (float*)(bsum + 256);                 // [NN]

    hipMemsetAsync(cnt_i, 0, NN * sizeof(int), stream);
    hipMemsetAsync(cursor, 0, NN * sizeof(int), stream);
    hist_kernel<<<(NE + 255) / 256, 256, 0, stream>>>(receivers, cnt_i);
    inv_kernel<<<(NN + 255) / 256, 256, 0, stream>>>(cnt_i, inv);
    scan1_kernel<<<196, 256, 0, stream>>>(cnt_i, row_start, bsum);
    scan2_kernel<<<1, 256, 0, stream>>>(bsum, 196);
    scan3_kernel<<<196, 256, 0, stream>>>(row_start, bsum);
    scatter_kernel<<<(NE + 255) / 256, 256, 0, stream>>>(senders, receivers, row_start,
                                                         cursor, eidx, sid, rid);

    for (int l = 0; l < 3; ++l) {
        const float* ncur = (l == 0) ? nodes : nodes_buf;
        const float* We_l = We + (size_t)l * 192 * 64;
        // [P|Q] = nodes @ [We[64:128] | We[128:192]]  (one A pass)
        gemm_pq_kernel<<<782, 256, 0, stream>>>(ncur, NN, We_l + 64 * 64, We_l + 128 * 64,
                                                Pbuf, Qbuf);
        // zero agg sums, then fused edge GEMM + aggregation (CSR order)
        hipMemsetAsync(aggbuf, 0, (size_t)NN * 64 * sizeof(float), stream);
        edge_csr_kernel<<<3125, 512, 0, stream>>>(
            (l == 0) ? edges : edges_buf,
            (l == 0) ? eidx : (const int*)nullptr,
            We_l, be + (size_t)l * 64, Pbuf, Qbuf,
            sid, rid, row_start, edges_buf, aggbuf);
        // nodes = relu([nodes | agg*inv] @ Wn + bn)
        node_kernel<<<391, 256, 0, stream>>>(ncur, aggbuf, inv,
                                             Wn + (size_t)l * 128 * 64, bn + (size_t)l * 64,
                                             nodes_buf);
    }
    final_kernel<<<625, 256, 0, stream>>>(nodes_buf, gamma, beta,
                                          W1, b1, W2, b2, Wp, bp, out);
}